// Round 1
// baseline (1339.410 us; speedup 1.0000x reference)
//
#include <hip/hip_runtime.h>
#include <stdint.h>

#define SR_F 16000.0f
#define NSAMP 160000
#define NB 128
#define FRAME 400
#define HOP 160
#define NF 998
#define NHNR_CHUNK 16
#define HNR_LAGS 150
#define HTILE 2000
#define HHALO 224

// workspace layout (float offsets)
#define OFF_RMS 0
#define OFF_ZCR (OFF_RMS + NB*NF)
#define OFF_AMP (OFF_ZCR + NB*NF)
#define OFF_F0  (OFF_AMP + NB*NF)
#define OFF_VAL (OFF_F0  + NB*NF)
#define OFF_JIT (OFF_VAL + NB*NF)            // NB*4
#define OFF_HNR (OFF_JIT + NB*4)             // NB*NHNR_CHUNK*HNR_LAGS

__device__ __forceinline__ int imax_(int a, int b) { return a > b ? a : b; }

// ---------------------------------------------------------------------------
// K1: per-frame stats + autocorr peak.  One 64-thread wave per frame.
// lane owns lags 5*lane .. 5*lane+4 (320 lags exactly).
// ---------------------------------------------------------------------------
__global__ __launch_bounds__(64) void k_frame(const float* __restrict__ audio,
                                              float* __restrict__ ws)
{
    __shared__ __align__(16) float sx[744];   // 400 data + zero pad (reads up to l0+415 <= 730)
    const int s = blockIdx.y, f = blockIdx.x;
    const int tid = threadIdx.x;
    const float* a = audio + (size_t)s * NSAMP + (size_t)f * HOP;

    for (int i = tid; i < 744; i += 64) sx[i] = (i < FRAME) ? a[i] : 0.f;
    __syncthreads();

    // ---- rms / zcr / amp ----
    float ss = 0.f, zc = 0.f, amp = 0.f;
    for (int k = 0; k < 7; ++k) {
        int t = tid + 64 * k;
        if (t < FRAME) {
            float v = sx[t];
            ss += v * v;
            amp = fmaxf(amp, fabsf(v));
            if (t < FRAME - 1) {
                float v2 = sx[t + 1];
                float sg1 = (float)(v  > 0.f) - (float)(v  < 0.f);
                float sg2 = (float)(v2 > 0.f) - (float)(v2 < 0.f);
                zc += fabsf(sg2 - sg1);
            }
        }
    }
    #pragma unroll
    for (int off = 32; off; off >>= 1) {
        ss += __shfl_xor(ss, off);
        zc += __shfl_xor(zc, off);
        amp = fmaxf(amp, __shfl_xor(amp, off));
    }

    // ---- autocorr, lags l0..l0+4, sliding 16-reg window, t unrolled by 16 ----
    const int l0 = 5 * tid;
    float acc[5] = {0.f, 0.f, 0.f, 0.f, 0.f};
    float w[16];
    #pragma unroll
    for (int i = 0; i < 16; ++i) w[i] = sx[l0 + i];

    for (int t = 0; t < FRAME; t += 16) {
        float4 b0 = *(const float4*)&sx[t];
        float4 b1 = *(const float4*)&sx[t + 4];
        float xb[8] = {b0.x, b0.y, b0.z, b0.w, b1.x, b1.y, b1.z, b1.w};
        #pragma unroll
        for (int d = 0; d < 8; ++d) {
            #pragma unroll
            for (int j = 0; j < 5; ++j)
                acc[j] = fmaf(xb[d], w[d + j], acc[j]);
        }
        #pragma unroll
        for (int i = 0; i < 8; ++i) w[i] = sx[l0 + t + 16 + i];

        float4 b2 = *(const float4*)&sx[t + 8];
        float4 b3 = *(const float4*)&sx[t + 12];
        float xc[8] = {b2.x, b2.y, b2.z, b2.w, b3.x, b3.y, b3.z, b3.w};
        #pragma unroll
        for (int d = 0; d < 8; ++d) {
            #pragma unroll
            for (int j = 0; j < 5; ++j)
                acc[j] = fmaf(xc[d], w[(8 + d + j) & 15], acc[j]);
        }
        #pragma unroll
        for (int i = 0; i < 8; ++i) w[8 + i] = sx[l0 + t + 24 + i];
    }

    float ac0 = __shfl(acc[0], 0);

    // first-max argmax over lags [32, 320)
    float bv = -1e30f; int bl = 1 << 30;
    #pragma unroll
    for (int j = 0; j < 5; ++j) {
        int lag = l0 + j;
        if (lag >= 32 && acc[j] > bv) { bv = acc[j]; bl = lag; }
    }
    #pragma unroll
    for (int off = 32; off; off >>= 1) {
        float ov = __shfl_xor(bv, off);
        int   ol = __shfl_xor(bl, off);
        if (ov > bv || (ov == bv && ol < bl)) { bv = ov; bl = ol; }
    }

    if (tid == 0) {
        float f0 = SR_F / (float)bl;
        int valid = (bv > 0.3f * ac0) && (f0 > 50.f) && (f0 < 500.f);
        size_t idx = (size_t)s * NF + f;
        ws[OFF_RMS + idx] = sqrtf(ss / (float)FRAME);
        ws[OFF_ZCR + idx] = zc / (2.f * (float)FRAME);
        ws[OFF_AMP + idx] = amp;
        ws[OFF_F0  + idx] = f0;
        ws[OFF_VAL + idx] = valid ? 1.f : 0.f;
    }
}

// ---------------------------------------------------------------------------
// K2: jitter — threshold crossings over whole waveform.  One block / sample.
// ---------------------------------------------------------------------------
__global__ __launch_bounds__(256) void k_jitter(const float* __restrict__ audio,
                                                float* __restrict__ ws)
{
    __shared__ unsigned long long msk[2500];   // 159999 flag bits
    __shared__ int   s_cnt[256], s_p0[256], s_p1[256], s_pl[256], s_pl2[256];
    __shared__ float s_sum[256];
    __shared__ float sred[4];
    __shared__ float s_thr;

    const int s = blockIdx.x;
    const int tid = threadIdx.x;
    const float* a = audio + (size_t)s * NSAMP;

    // max |a|
    float m = 0.f;
    for (int i = tid; i < NSAMP; i += 256) m = fmaxf(m, fabsf(a[i]));
    #pragma unroll
    for (int off = 32; off; off >>= 1) m = fmaxf(m, __shfl_xor(m, off));
    if ((tid & 63) == 0) sred[tid >> 6] = m;
    __syncthreads();
    if (tid == 0)
        s_thr = 0.3f * fmaxf(fmaxf(sred[0], sred[1]), fmaxf(sred[2], sred[3]));
    __syncthreads();
    const float thr = s_thr;

    // crossing flags -> bitmask (coalesced)
    for (int base = 0; base < NSAMP - 1; base += 256) {
        int i = base + tid;
        bool fl = (i < NSAMP - 1) && (a[i] < thr) && (a[i + 1] >= thr);
        unsigned long long bal = __ballot(fl);
        if ((tid & 63) == 0) msk[(base + tid) >> 6] = bal;
    }
    __syncthreads();

    // chunk states: 250 chunks x 10 u64 words
    int cnt = 0, p0 = 0, p1 = 0, pl = 0, pl2 = 0;
    float sum = 0.f;
    if (tid < 250) {
        for (int wi = 0; wi < 10; ++wi) {
            unsigned long long word = msk[tid * 10 + wi];
            int wb = (tid * 10 + wi) << 6;
            while (word) {
                int b = __builtin_ctzll(word);
                word &= word - 1;
                int pos = wb + b + 1;     // crossing position index i (a[i] first >= thr)
                if (cnt >= 2) sum += fabsf((float)((pos - pl) - (pl - pl2)));
                if (cnt == 0) p0 = pos;
                if (cnt == 1) p1 = pos;
                pl2 = pl; pl = pos; ++cnt;
            }
        }
    }
    s_cnt[tid] = cnt; s_p0[tid] = p0; s_p1[tid] = p1;
    s_pl[tid] = pl; s_pl2[tid] = pl2; s_sum[tid] = sum;
    __syncthreads();

    if (tid == 0) {
        int Ac = 0, Ap0 = 0, Ap1 = 0, Apl = 0, Apl2 = 0; float As = 0.f;
        for (int c = 0; c < 250; ++c) {
            int rc = s_cnt[c]; if (!rc) continue;
            int rp0 = s_p0[c], rp1 = s_p1[c], rpl = s_pl[c], rpl2 = s_pl2[c];
            float rs = s_sum[c];
            if (Ac == 0) { Ac = rc; Ap0 = rp0; Ap1 = rp1; Apl = rpl; Apl2 = rpl2; As = rs; continue; }
            int pb = rp0 - Apl;                        // boundary period
            As += rs;
            if (Ac >= 2) As += fabsf((float)(pb - (Apl - Apl2)));
            if (rc >= 2) As += fabsf((float)((rp1 - rp0) - pb));
            if (Ac == 1) Ap1 = rp0;
            Apl2 = (rc >= 2) ? rpl2 : Apl;
            Apl = rpl;
            Ac += rc;
        }
        float* j = ws + OFF_JIT + s * 4;
        j[0] = (float)Ac; j[1] = (float)Ap0; j[2] = (float)Apl; j[3] = As;
    }
}

// ---------------------------------------------------------------------------
// K3: HNR partial autocorr, lags 50..199.  grid (chunk, sample), 64 threads.
// lane owns lags 50+3*lane .. +2 (lanes 0..49 active).
// ---------------------------------------------------------------------------
__global__ __launch_bounds__(64) void k_hnr(const float* __restrict__ audio,
                                            float* __restrict__ ws)
{
    __shared__ __align__(16) float sx[HTILE + HHALO];
    const int s = blockIdx.y, c = blockIdx.x;
    const int tid = threadIdx.x;
    const float* a = audio + (size_t)s * NSAMP;
    const int base = c * (NSAMP / NHNR_CHUNK);          // 10000
    const int l0 = 50 + 3 * ((tid < 50) ? tid : 0);     // idle lanes duplicate lane 0

    float acc[3] = {0.f, 0.f, 0.f};
    for (int tile = 0; tile < (NSAMP / NHNR_CHUNK) / HTILE; ++tile) {
        const int tb = base + tile * HTILE;
        for (int i = tid; i < HTILE + HHALO; i += 64) {
            int g = tb + i;
            sx[i] = (g < NSAMP) ? a[g] : 0.f;
        }
        __syncthreads();

        float w[16];
        #pragma unroll
        for (int i = 0; i < 16; ++i) w[i] = sx[l0 + i];
        for (int t = 0; t < HTILE; t += 16) {
            float4 b0 = *(const float4*)&sx[t];
            float4 b1 = *(const float4*)&sx[t + 4];
            float xb[8] = {b0.x, b0.y, b0.z, b0.w, b1.x, b1.y, b1.z, b1.w};
            #pragma unroll
            for (int d = 0; d < 8; ++d) {
                #pragma unroll
                for (int j = 0; j < 3; ++j)
                    acc[j] = fmaf(xb[d], w[d + j], acc[j]);
            }
            #pragma unroll
            for (int i = 0; i < 8; ++i) w[i] = sx[l0 + t + 16 + i];

            float4 b2 = *(const float4*)&sx[t + 8];
            float4 b3 = *(const float4*)&sx[t + 12];
            float xc[8] = {b2.x, b2.y, b2.z, b2.w, b3.x, b3.y, b3.z, b3.w};
            #pragma unroll
            for (int d = 0; d < 8; ++d) {
                #pragma unroll
                for (int j = 0; j < 3; ++j)
                    acc[j] = fmaf(xc[d], w[(8 + d + j) & 15], acc[j]);
            }
            #pragma unroll
            for (int i = 0; i < 8; ++i) w[8 + i] = sx[l0 + t + 24 + i];
        }
        __syncthreads();
    }
    if (tid < 50) {
        float* p = ws + OFF_HNR + ((size_t)s * NHNR_CHUNK + c) * HNR_LAGS + 3 * tid;
        p[0] = acc[0]; p[1] = acc[1]; p[2] = acc[2];
    }
}

// ---------------------------------------------------------------------------
// K4: per-sample finalize (stats, shimmer, jitter gate, HNR percentile) + MLP
// ---------------------------------------------------------------------------
__global__ __launch_bounds__(256) void k_final(const float* __restrict__ ws,
        const float* __restrict__ W1, const float* __restrict__ b1,
        const float* __restrict__ gam, const float* __restrict__ bet,
        const float* __restrict__ W2, const float* __restrict__ b2,
        float* __restrict__ out)
{
    __shared__ float samp[NF];
    __shared__ float sac[HNR_LAGS];
    __shared__ float sred[32];
    __shared__ float sstat[12];
    __shared__ float sfeats[10];
    __shared__ float shid[64];

    const int s = blockIdx.x;
    const int tid = threadIdx.x;
    const float* rmsA = ws + OFF_RMS + (size_t)s * NF;
    const float* zcrA = ws + OFF_ZCR + (size_t)s * NF;
    const float* ampA = ws + OFF_AMP + (size_t)s * NF;
    const float* f0A  = ws + OFF_F0  + (size_t)s * NF;
    const float* valA = ws + OFF_VAL + (size_t)s * NF;

    float a0=0,a1=0,a2=0,a3=0,a4=0,a5=0,a6=0,a7=0;
    for (int i = tid; i < NF; i += 256) {
        float r = rmsA[i], z = zcrA[i], f0 = f0A[i], v = valA[i];
        samp[i] = ampA[i];
        a0 += r; a1 += r * r; a2 += z; a3 += z * z;
        a4 += f0 * v; a5 += f0 * f0 * v; a6 += v;
        a7 += (r > 0.01f && z < 0.3f) ? 1.f : 0.f;
    }
    #pragma unroll
    for (int off = 32; off; off >>= 1) {
        a0 += __shfl_xor(a0, off); a1 += __shfl_xor(a1, off);
        a2 += __shfl_xor(a2, off); a3 += __shfl_xor(a3, off);
        a4 += __shfl_xor(a4, off); a5 += __shfl_xor(a5, off);
        a6 += __shfl_xor(a6, off); a7 += __shfl_xor(a7, off);
    }
    if ((tid & 63) == 0) {
        int w = tid >> 6;
        sred[w*8+0]=a0; sred[w*8+1]=a1; sred[w*8+2]=a2; sred[w*8+3]=a3;
        sred[w*8+4]=a4; sred[w*8+5]=a5; sred[w*8+6]=a6; sred[w*8+7]=a7;
    }
    __syncthreads();

    if (tid < HNR_LAGS) {
        float acc = 0.f;
        const float* p = ws + OFF_HNR + (size_t)s * NHNR_CHUNK * HNR_LAGS + tid;
        for (int c = 0; c < NHNR_CHUNK; ++c) acc += p[c * HNR_LAGS];
        sac[tid] = acc;
    }
    if (tid == 0) {
        for (int k = 0; k < 8; ++k)
            sstat[k] = sred[k] + sred[8+k] + sred[16+k] + sred[24+k];
    }
    __syncthreads();

    // exact 10th-percentile (linear interp): stable ranks, pick rank 14 & 15
    if (tid < HNR_LAGS) {
        float v = sac[tid];
        int r = 0;
        for (int j = 0; j < HNR_LAGS; ++j) {
            float vj = sac[j];
            r += (vj < v) || (vj == v && j < tid);
        }
        if (r == 14) sstat[8] = v;
        if (r == 15) sstat[9] = v;
    }
    if (tid == 192) {
        float mx = sac[0];
        for (int j = 1; j < HNR_LAGS; ++j) mx = fmaxf(mx, sac[j]);
        sstat[10] = mx;
    }
    if (tid == 224) {
        // shimmer: serial scan over retained amps
        int ka = 0; float sum_amp = 0.f, sum_ad = 0.f, prev = 0.f;
        for (int i = 0; i < NF; ++i) {
            float amp = samp[i];
            if (amp > 0.01f) {
                if (ka >= 1) sum_ad += fabsf(amp - prev);
                sum_amp += amp; prev = amp; ++ka;
            }
        }
        float mean_amp = sum_amp / (float)imax_(ka, 1);
        float mean_ad  = sum_ad  / (float)imax_(ka - 1, 1);
        sstat[11] = (ka >= 2 && mean_amp > 0.f)
            ? fminf(fmaxf(mean_ad / fmaxf(mean_amp, 1e-12f), 0.f), 1.f) : 0.f;
    }
    __syncthreads();

    if (tid == 0) {
        float S_r = sstat[0], S_r2 = sstat[1], S_z = sstat[2], S_z2 = sstat[3];
        float S_f = sstat[4], S_f2 = sstat[5], S_v = sstat[6], S_voi = sstat[7];
        float e_mean = S_r / (float)NF;
        float e_std  = sqrtf(fmaxf(S_r2 / (float)NF - e_mean * e_mean, 0.f));
        float z_mean = S_z / (float)NF;
        float z_std  = sqrtf(fmaxf(S_z2 / (float)NF - z_mean * z_mean, 0.f));
        float f0_mean = 0.f, f0_std = 0.f;
        if (S_v > 0.f) {
            f0_mean = S_f / S_v;
            f0_std  = sqrtf(fmaxf(S_f2 / S_v - f0_mean * f0_mean, 0.f));
        }
        // jitter
        const float* jp = ws + OFF_JIT + s * 4;
        int k = (int)jp[0];
        float pp0 = jp[1], ppl = jp[2], psum = jp[3];
        int nper = k - 1;
        float mean_period = (k >= 2) ? (ppl - pp0) / (float)(k - 1) : 0.f;
        float mean_pd = psum / (float)imax_(nper - 1, 1);
        float jit = (nper >= 2 && mean_period > 0.f)
            ? fminf(fmaxf(mean_pd / fmaxf(mean_period, 1e-12f), 0.f), 1.f) : 0.f;
        if (f0_mean < 50.f || f0_mean > 500.f) jit = 0.f;
        // hnr
        float noise = 0.1f * sstat[8] + 0.9f * sstat[9];
        float hnr = (noise > 0.f)
            ? fminf(fmaxf(sstat[10] / fmaxf(noise, 1e-30f) / 100.f, 0.f), 1.f) : 0.f;
        float shim = sstat[11];
        float voice = S_voi / (float)NF;

        float mt[10] = {f0_mean, f0_std, e_mean, e_std, z_mean, z_std, jit, shim, hnr, voice};
        for (int i = 0; i < 10; ++i) out[NB * 128 + s * 10 + i] = mt[i];
        sfeats[0] = f0_mean / 500.f;
        sfeats[1] = f0_std / 100.f;
        for (int i = 2; i < 10; ++i) sfeats[i] = mt[i];
    }
    __syncthreads();

    // projection: 10 -> 64 (LN, relu) -> 128
    if (tid < 64) {
        float h = b1[tid];
        #pragma unroll
        for (int i = 0; i < 10; ++i) h = fmaf(sfeats[i], W1[tid * 10 + i], h);
        float sum = h, sq = h * h;
        #pragma unroll
        for (int off = 32; off; off >>= 1) {
            sum += __shfl_xor(sum, off);
            sq  += __shfl_xor(sq, off);
        }
        float mu = sum / 64.f;
        float var = sq / 64.f - mu * mu;
        float hn = (h - mu) * rsqrtf(var + 1e-5f) * gam[tid] + bet[tid];
        shid[tid] = fmaxf(hn, 0.f);
    }
    __syncthreads();
    if (tid < 128) {
        float accv = b2[tid];
        #pragma unroll 8
        for (int j = 0; j < 64; ++j) accv = fmaf(shid[j], W2[tid * 64 + j], accv);
        out[(size_t)s * 128 + tid] = accv;
    }
}

// ---------------------------------------------------------------------------
extern "C" void kernel_launch(void* const* d_in, const int* in_sizes, int n_in,
                              void* d_out, int out_size, void* d_ws, size_t ws_size,
                              hipStream_t stream)
{
    const float* audio = (const float*)d_in[0];
    const float* W1    = (const float*)d_in[1];
    const float* b1    = (const float*)d_in[2];
    const float* gam   = (const float*)d_in[3];
    const float* bet   = (const float*)d_in[4];
    const float* W2    = (const float*)d_in[5];
    const float* b2    = (const float*)d_in[6];
    float* out = (float*)d_out;
    float* ws  = (float*)d_ws;

    hipLaunchKernelGGL(k_frame,  dim3(NF, NB),         dim3(64),  0, stream, audio, ws);
    hipLaunchKernelGGL(k_jitter, dim3(NB),             dim3(256), 0, stream, audio, ws);
    hipLaunchKernelGGL(k_hnr,    dim3(NHNR_CHUNK, NB), dim3(64),  0, stream, audio, ws);
    hipLaunchKernelGGL(k_final,  dim3(NB),             dim3(256), 0, stream,
                       ws, W1, b1, gam, bet, W2, b2, out);
}

// Round 2
// 962.449 us; speedup vs baseline: 1.3917x; 1.3917x over previous
//
#include <hip/hip_runtime.h>
#include <stdint.h>

#define SR_F 16000.0f
#define NSAMP 160000
#define NB 128
#define FRAME 400
#define HOP 160
#define NF 998
#define NHNR_CHUNK 40
#define HCH 4000            // samples per hnr chunk (40*4000 = 160000)
#define HNR_LAGS 150
#define HTILE 800
#define HHALO 224           // >= 199 + 24 + 7 - 16 = 214? need l0max+ (t+24+7): 197+784+31-? covered: 1024 row

// workspace layout (float offsets)
#define OFF_RMS 0
#define OFF_ZCR (OFF_RMS + NB*NF)
#define OFF_AMP (OFF_ZCR + NB*NF)
#define OFF_F0  (OFF_AMP + NB*NF)
#define OFF_VAL (OFF_F0  + NB*NF)
#define OFF_JIT (OFF_VAL + NB*NF)            // NB*4
#define OFF_HNR (OFF_JIT + NB*4)             // NB*NHNR_CHUNK*HNR_LAGS

__device__ __forceinline__ int imax_(int a, int b) { return a > b ? a : b; }

// ---------------------------------------------------------------------------
// K1: per-frame stats + autocorr peak.  256 threads = 4 waves, 1 frame/wave.
// lane owns lags 5*lane .. 5*lane+4 (320 lags exactly).
// ---------------------------------------------------------------------------
__global__ __launch_bounds__(256) void k_frame(const float* __restrict__ audio,
                                               float* __restrict__ ws)
{
    __shared__ __align__(16) float sx[4][744];   // 400 data + zero pad per wave
    const int tid = threadIdx.x;
    const int widx = tid >> 6, lane = tid & 63;
    const int s = blockIdx.y;
    const int f = blockIdx.x * 4 + widx;

    if (f < NF) {
        const float* a = audio + (size_t)s * NSAMP + (size_t)f * HOP;
        float4* smv = (float4*)sx[widx];
        for (int v = lane; v < 186; v += 64) {       // 744/4
            float4 val;
            if (v < 100) val = ((const float4*)a)[v];
            else { val.x = 0.f; val.y = 0.f; val.z = 0.f; val.w = 0.f; }
            smv[v] = val;
        }
    }
    __syncthreads();
    if (f >= NF) return;

    const float* sm = sx[widx];

    // ---- rms / zcr / amp ----
    float ss = 0.f, zc = 0.f, amp = 0.f;
    for (int k = 0; k < 7; ++k) {
        int t = lane + 64 * k;
        if (t < FRAME) {
            float v = sm[t];
            ss += v * v;
            amp = fmaxf(amp, fabsf(v));
            if (t < FRAME - 1) {
                float v2 = sm[t + 1];
                float sg1 = (float)(v  > 0.f) - (float)(v  < 0.f);
                float sg2 = (float)(v2 > 0.f) - (float)(v2 < 0.f);
                zc += fabsf(sg2 - sg1);
            }
        }
    }
    #pragma unroll
    for (int off = 32; off; off >>= 1) {
        ss += __shfl_xor(ss, off);
        zc += __shfl_xor(zc, off);
        amp = fmaxf(amp, __shfl_xor(amp, off));
    }

    // ---- autocorr, lags l0..l0+4, sliding 16-reg window, t unrolled by 16 ----
    const int l0 = 5 * lane;
    float acc[5] = {0.f, 0.f, 0.f, 0.f, 0.f};
    float w[16];
    #pragma unroll
    for (int i = 0; i < 16; ++i) w[i] = sm[l0 + i];

    #pragma unroll 5
    for (int t = 0; t < FRAME; t += 16) {
        float4 b0 = *(const float4*)&sm[t];
        float4 b1 = *(const float4*)&sm[t + 4];
        float xb[8] = {b0.x, b0.y, b0.z, b0.w, b1.x, b1.y, b1.z, b1.w};
        #pragma unroll
        for (int d = 0; d < 8; ++d) {
            #pragma unroll
            for (int j = 0; j < 5; ++j)
                acc[j] = fmaf(xb[d], w[d + j], acc[j]);
        }
        #pragma unroll
        for (int i = 0; i < 8; ++i) w[i] = sm[l0 + t + 16 + i];

        float4 b2 = *(const float4*)&sm[t + 8];
        float4 b3 = *(const float4*)&sm[t + 12];
        float xc[8] = {b2.x, b2.y, b2.z, b2.w, b3.x, b3.y, b3.z, b3.w};
        #pragma unroll
        for (int d = 0; d < 8; ++d) {
            #pragma unroll
            for (int j = 0; j < 5; ++j)
                acc[j] = fmaf(xc[d], w[(8 + d + j) & 15], acc[j]);
        }
        #pragma unroll
        for (int i = 0; i < 8; ++i) w[8 + i] = sm[l0 + t + 24 + i];
    }

    float ac0 = __shfl(acc[0], 0);

    // first-max argmax over lags [32, 320)
    float bv = -1e30f; int bl = 1 << 30;
    #pragma unroll
    for (int j = 0; j < 5; ++j) {
        int lag = l0 + j;
        if (lag >= 32 && acc[j] > bv) { bv = acc[j]; bl = lag; }
    }
    #pragma unroll
    for (int off = 32; off; off >>= 1) {
        float ov = __shfl_xor(bv, off);
        int   ol = __shfl_xor(bl, off);
        if (ov > bv || (ov == bv && ol < bl)) { bv = ov; bl = ol; }
    }

    if (lane == 0) {
        float f0 = SR_F / (float)bl;
        int valid = (bv > 0.3f * ac0) && (f0 > 50.f) && (f0 < 500.f);
        size_t idx = (size_t)s * NF + f;
        ws[OFF_RMS + idx] = sqrtf(ss / (float)FRAME);
        ws[OFF_ZCR + idx] = zc / (2.f * (float)FRAME);
        ws[OFF_AMP + idx] = amp;
        ws[OFF_F0  + idx] = f0;
        ws[OFF_VAL + idx] = valid ? 1.f : 0.f;
    }
}

// ---------------------------------------------------------------------------
// K2: jitter — threshold crossings over whole waveform.  One block / sample.
// 1024 threads (16 waves) for latency cover on the two global passes.
// ---------------------------------------------------------------------------
__global__ __launch_bounds__(1024) void k_jitter(const float* __restrict__ audio,
                                                 float* __restrict__ ws)
{
    __shared__ unsigned long long msk[2500];   // 159999 flag bits
    __shared__ int   s_cnt[256], s_p0[256], s_p1[256], s_pl[256], s_pl2[256];
    __shared__ float s_sum[256];
    __shared__ float sred[16];
    __shared__ float s_thr;

    const int s = blockIdx.x;
    const int tid = threadIdx.x;
    const float* a = audio + (size_t)s * NSAMP;

    // max |a|
    float m = 0.f;
    for (int i = tid; i < NSAMP; i += 1024) m = fmaxf(m, fabsf(a[i]));
    #pragma unroll
    for (int off = 32; off; off >>= 1) m = fmaxf(m, __shfl_xor(m, off));
    if ((tid & 63) == 0) sred[tid >> 6] = m;
    __syncthreads();
    if (tid == 0) {
        float mm = sred[0];
        for (int i = 1; i < 16; ++i) mm = fmaxf(mm, sred[i]);
        s_thr = 0.3f * mm;
    }
    __syncthreads();
    const float thr = s_thr;

    // crossing flags -> bitmask (coalesced)
    for (int base = 0; base < NSAMP - 1; base += 1024) {
        int i = base + tid;
        bool fl = (i < NSAMP - 1) && (a[i] < thr) && (a[i + 1] >= thr);
        unsigned long long bal = __ballot(fl);
        if ((tid & 63) == 0 && (base + tid) < NSAMP) msk[(base + tid) >> 6] = bal;
    }
    __syncthreads();

    // chunk states: 250 chunks x 10 u64 words
    if (tid < 250) {
        int cnt = 0, p0 = 0, p1 = 0, pl = 0, pl2 = 0;
        float sum = 0.f;
        for (int wi = 0; wi < 10; ++wi) {
            unsigned long long word = msk[tid * 10 + wi];
            int wb = (tid * 10 + wi) << 6;
            while (word) {
                int b = __builtin_ctzll(word);
                word &= word - 1;
                int pos = wb + b + 1;     // crossing index i (a[i] first >= thr)
                if (cnt >= 2) sum += fabsf((float)((pos - pl) - (pl - pl2)));
                if (cnt == 0) p0 = pos;
                if (cnt == 1) p1 = pos;
                pl2 = pl; pl = pos; ++cnt;
            }
        }
        s_cnt[tid] = cnt; s_p0[tid] = p0; s_p1[tid] = p1;
        s_pl[tid] = pl; s_pl2[tid] = pl2; s_sum[tid] = sum;
    }
    __syncthreads();

    if (tid == 0) {
        int Ac = 0, Ap0 = 0, Ap1 = 0, Apl = 0, Apl2 = 0; float As = 0.f;
        for (int c = 0; c < 250; ++c) {
            int rc = s_cnt[c]; if (!rc) continue;
            int rp0 = s_p0[c], rp1 = s_p1[c], rpl = s_pl[c], rpl2 = s_pl2[c];
            float rs = s_sum[c];
            if (Ac == 0) { Ac = rc; Ap0 = rp0; Ap1 = rp1; Apl = rpl; Apl2 = rpl2; As = rs; continue; }
            int pb = rp0 - Apl;                        // boundary period
            As += rs;
            if (Ac >= 2) As += fabsf((float)(pb - (Apl - Apl2)));
            if (rc >= 2) As += fabsf((float)((rp1 - rp0) - pb));
            if (Ac == 1) Ap1 = rp0;
            Apl2 = (rc >= 2) ? rpl2 : Apl;
            Apl = rpl;
            Ac += rc;
        }
        float* j = ws + OFF_JIT + s * 4;
        j[0] = (float)Ac; j[1] = (float)Ap0; j[2] = (float)Apl; j[3] = As;
    }
}

// ---------------------------------------------------------------------------
// K3: HNR partial autocorr, lags 50..199.  256 threads = 4 waves, 1 chunk/wave.
// 40 chunks of 4000 samples; 5 tiles of 800 per chunk.
// lane owns lags 50+3*lane .. +2 (lanes 0..49 active).
// ---------------------------------------------------------------------------
__global__ __launch_bounds__(256) void k_hnr(const float* __restrict__ audio,
                                             float* __restrict__ ws)
{
    __shared__ __align__(16) float sx[4][HTILE + HHALO];  // 1024 floats per wave
    const int tid = threadIdx.x;
    const int widx = tid >> 6, lane = tid & 63;
    const int s = blockIdx.y;
    const int c = blockIdx.x * 4 + widx;                  // chunk id, < 40
    const float* a = audio + (size_t)s * NSAMP;
    const int l0 = 50 + 3 * ((lane < 50) ? lane : 0);     // idle lanes duplicate lane 0
    float* sm = sx[widx];

    float acc[3] = {0.f, 0.f, 0.f};
    for (int tile = 0; tile < HCH / HTILE; ++tile) {
        const int tb = c * HCH + tile * HTILE;
        __syncthreads();
        {
            float4* smv = (float4*)sm;
            for (int v = lane; v < (HTILE + HHALO) / 4; v += 64) {
                int g = tb + 4 * v;
                float4 val;
                if (g + 3 < NSAMP) val = *(const float4*)(a + g);
                else {
                    val.x = (g     < NSAMP) ? a[g]     : 0.f;
                    val.y = (g + 1 < NSAMP) ? a[g + 1] : 0.f;
                    val.z = (g + 2 < NSAMP) ? a[g + 2] : 0.f;
                    val.w = (g + 3 < NSAMP) ? a[g + 3] : 0.f;
                }
                smv[v] = val;
            }
        }
        __syncthreads();

        float w[16];
        #pragma unroll
        for (int i = 0; i < 16; ++i) w[i] = sm[l0 + i];
        for (int t = 0; t < HTILE; t += 16) {
            float4 b0 = *(const float4*)&sm[t];
            float4 b1 = *(const float4*)&sm[t + 4];
            float xb[8] = {b0.x, b0.y, b0.z, b0.w, b1.x, b1.y, b1.z, b1.w};
            #pragma unroll
            for (int d = 0; d < 8; ++d) {
                #pragma unroll
                for (int j = 0; j < 3; ++j)
                    acc[j] = fmaf(xb[d], w[d + j], acc[j]);
            }
            #pragma unroll
            for (int i = 0; i < 8; ++i) w[i] = sm[l0 + t + 16 + i];

            float4 b2 = *(const float4*)&sm[t + 8];
            float4 b3 = *(const float4*)&sm[t + 12];
            float xc[8] = {b2.x, b2.y, b2.z, b2.w, b3.x, b3.y, b3.z, b3.w};
            #pragma unroll
            for (int d = 0; d < 8; ++d) {
                #pragma unroll
                for (int j = 0; j < 3; ++j)
                    acc[j] = fmaf(xc[d], w[(8 + d + j) & 15], acc[j]);
            }
            #pragma unroll
            for (int i = 0; i < 8; ++i) w[8 + i] = sm[l0 + t + 24 + i];
        }
    }
    if (lane < 50) {
        float* p = ws + OFF_HNR + ((size_t)s * NHNR_CHUNK + c) * HNR_LAGS + 3 * lane;
        p[0] = acc[0]; p[1] = acc[1]; p[2] = acc[2];
    }
}

// ---------------------------------------------------------------------------
// K4: per-sample finalize (stats, shimmer, jitter gate, HNR percentile) + MLP
// ---------------------------------------------------------------------------
__global__ __launch_bounds__(256) void k_final(const float* __restrict__ ws,
        const float* __restrict__ W1, const float* __restrict__ b1,
        const float* __restrict__ gam, const float* __restrict__ bet,
        const float* __restrict__ W2, const float* __restrict__ b2,
        float* __restrict__ out)
{
    __shared__ float samp[NF];
    __shared__ float sac[HNR_LAGS];
    __shared__ float sred[32];
    __shared__ float sstat[12];
    __shared__ float sfeats[10];
    __shared__ float shid[64];

    const int s = blockIdx.x;
    const int tid = threadIdx.x;
    const float* rmsA = ws + OFF_RMS + (size_t)s * NF;
    const float* zcrA = ws + OFF_ZCR + (size_t)s * NF;
    const float* ampA = ws + OFF_AMP + (size_t)s * NF;
    const float* f0A  = ws + OFF_F0  + (size_t)s * NF;
    const float* valA = ws + OFF_VAL + (size_t)s * NF;

    float a0=0,a1=0,a2=0,a3=0,a4=0,a5=0,a6=0,a7=0;
    for (int i = tid; i < NF; i += 256) {
        float r = rmsA[i], z = zcrA[i], f0 = f0A[i], v = valA[i];
        samp[i] = ampA[i];
        a0 += r; a1 += r * r; a2 += z; a3 += z * z;
        a4 += f0 * v; a5 += f0 * f0 * v; a6 += v;
        a7 += (r > 0.01f && z < 0.3f) ? 1.f : 0.f;
    }
    #pragma unroll
    for (int off = 32; off; off >>= 1) {
        a0 += __shfl_xor(a0, off); a1 += __shfl_xor(a1, off);
        a2 += __shfl_xor(a2, off); a3 += __shfl_xor(a3, off);
        a4 += __shfl_xor(a4, off); a5 += __shfl_xor(a5, off);
        a6 += __shfl_xor(a6, off); a7 += __shfl_xor(a7, off);
    }
    if ((tid & 63) == 0) {
        int w = tid >> 6;
        sred[w*8+0]=a0; sred[w*8+1]=a1; sred[w*8+2]=a2; sred[w*8+3]=a3;
        sred[w*8+4]=a4; sred[w*8+5]=a5; sred[w*8+6]=a6; sred[w*8+7]=a7;
    }
    __syncthreads();

    if (tid < HNR_LAGS) {
        float acc = 0.f;
        const float* p = ws + OFF_HNR + (size_t)s * NHNR_CHUNK * HNR_LAGS + tid;
        for (int c = 0; c < NHNR_CHUNK; ++c) acc += p[c * HNR_LAGS];
        sac[tid] = acc;
    }
    if (tid == 0) {
        for (int k = 0; k < 8; ++k)
            sstat[k] = sred[k] + sred[8+k] + sred[16+k] + sred[24+k];
    }
    __syncthreads();

    // exact 10th-percentile (linear interp): stable ranks, pick rank 14 & 15
    if (tid < HNR_LAGS) {
        float v = sac[tid];
        int r = 0;
        for (int j = 0; j < HNR_LAGS; ++j) {
            float vj = sac[j];
            r += (vj < v) || (vj == v && j < tid);
        }
        if (r == 14) sstat[8] = v;
        if (r == 15) sstat[9] = v;
    }
    if (tid == 192) {
        float mx = sac[0];
        for (int j = 1; j < HNR_LAGS; ++j) mx = fmaxf(mx, sac[j]);
        sstat[10] = mx;
    }
    if (tid == 224) {
        // shimmer: serial scan over retained amps
        int ka = 0; float sum_amp = 0.f, sum_ad = 0.f, prev = 0.f;
        for (int i = 0; i < NF; ++i) {
            float amp = samp[i];
            if (amp > 0.01f) {
                if (ka >= 1) sum_ad += fabsf(amp - prev);
                sum_amp += amp; prev = amp; ++ka;
            }
        }
        float mean_amp = sum_amp / (float)imax_(ka, 1);
        float mean_ad  = sum_ad  / (float)imax_(ka - 1, 1);
        sstat[11] = (ka >= 2 && mean_amp > 0.f)
            ? fminf(fmaxf(mean_ad / fmaxf(mean_amp, 1e-12f), 0.f), 1.f) : 0.f;
    }
    __syncthreads();

    if (tid == 0) {
        float S_r = sstat[0], S_r2 = sstat[1], S_z = sstat[2], S_z2 = sstat[3];
        float S_f = sstat[4], S_f2 = sstat[5], S_v = sstat[6], S_voi = sstat[7];
        float e_mean = S_r / (float)NF;
        float e_std  = sqrtf(fmaxf(S_r2 / (float)NF - e_mean * e_mean, 0.f));
        float z_mean = S_z / (float)NF;
        float z_std  = sqrtf(fmaxf(S_z2 / (float)NF - z_mean * z_mean, 0.f));
        float f0_mean = 0.f, f0_std = 0.f;
        if (S_v > 0.f) {
            f0_mean = S_f / S_v;
            f0_std  = sqrtf(fmaxf(S_f2 / S_v - f0_mean * f0_mean, 0.f));
        }
        // jitter
        const float* jp = ws + OFF_JIT + s * 4;
        int k = (int)jp[0];
        float pp0 = jp[1], ppl = jp[2], psum = jp[3];
        int nper = k - 1;
        float mean_period = (k >= 2) ? (ppl - pp0) / (float)(k - 1) : 0.f;
        float mean_pd = psum / (float)imax_(nper - 1, 1);
        float jit = (nper >= 2 && mean_period > 0.f)
            ? fminf(fmaxf(mean_pd / fmaxf(mean_period, 1e-12f), 0.f), 1.f) : 0.f;
        if (f0_mean < 50.f || f0_mean > 500.f) jit = 0.f;
        // hnr
        float noise = 0.1f * sstat[8] + 0.9f * sstat[9];
        float hnr = (noise > 0.f)
            ? fminf(fmaxf(sstat[10] / fmaxf(noise, 1e-30f) / 100.f, 0.f), 1.f) : 0.f;
        float shim = sstat[11];
        float voice = S_voi / (float)NF;

        float mt[10] = {f0_mean, f0_std, e_mean, e_std, z_mean, z_std, jit, shim, hnr, voice};
        for (int i = 0; i < 10; ++i) out[NB * 128 + s * 10 + i] = mt[i];
        sfeats[0] = f0_mean / 500.f;
        sfeats[1] = f0_std / 100.f;
        for (int i = 2; i < 10; ++i) sfeats[i] = mt[i];
    }
    __syncthreads();

    // projection: 10 -> 64 (LN, relu) -> 128
    if (tid < 64) {
        float h = b1[tid];
        #pragma unroll
        for (int i = 0; i < 10; ++i) h = fmaf(sfeats[i], W1[tid * 10 + i], h);
        float sum = h, sq = h * h;
        #pragma unroll
        for (int off = 32; off; off >>= 1) {
            sum += __shfl_xor(sum, off);
            sq  += __shfl_xor(sq, off);
        }
        float mu = sum / 64.f;
        float var = sq / 64.f - mu * mu;
        float hn = (h - mu) * rsqrtf(var + 1e-5f) * gam[tid] + bet[tid];
        shid[tid] = fmaxf(hn, 0.f);
    }
    __syncthreads();
    if (tid < 128) {
        float accv = b2[tid];
        #pragma unroll 8
        for (int j = 0; j < 64; ++j) accv = fmaf(shid[j], W2[tid * 64 + j], accv);
        out[(size_t)s * 128 + tid] = accv;
    }
}

// ---------------------------------------------------------------------------
extern "C" void kernel_launch(void* const* d_in, const int* in_sizes, int n_in,
                              void* d_out, int out_size, void* d_ws, size_t ws_size,
                              hipStream_t stream)
{
    const float* audio = (const float*)d_in[0];
    const float* W1    = (const float*)d_in[1];
    const float* b1    = (const float*)d_in[2];
    const float* gam   = (const float*)d_in[3];
    const float* bet   = (const float*)d_in[4];
    const float* W2    = (const float*)d_in[5];
    const float* b2    = (const float*)d_in[6];
    float* out = (float*)d_out;
    float* ws  = (float*)d_ws;

    hipLaunchKernelGGL(k_frame,  dim3((NF + 3) / 4, NB),          dim3(256),  0, stream, audio, ws);
    hipLaunchKernelGGL(k_jitter, dim3(NB),                        dim3(1024), 0, stream, audio, ws);
    hipLaunchKernelGGL(k_hnr,    dim3(NHNR_CHUNK / 4, NB),        dim3(256),  0, stream, audio, ws);
    hipLaunchKernelGGL(k_final,  dim3(NB),                        dim3(256),  0, stream,
                       ws, W1, b1, gam, bet, W2, b2, out);
}

// Round 3
// 515.018 us; speedup vs baseline: 2.6007x; 1.8688x over previous
//
#include <hip/hip_runtime.h>
#include <stdint.h>

typedef unsigned int uint;
typedef unsigned short ushort;
typedef __attribute__((ext_vector_type(8))) short bf16x8;
typedef __attribute__((ext_vector_type(4))) float f32x4;

#define SR_F 16000.0f
#define NSAMP 160000
#define NB 128
#define FRAME 400
#define HOP 160
#define NF 998
#define NHNR_CHUNK 40
#define JCH 125              // j-steps (32 samples each) per hnr chunk: 40*125*32 = 160000
#define HNR_LAGS 150
#define TJ 25                // j-steps per hnr tile (800 samples)
#define HWIN (32*TJ + 304)   // 1104 elems: 288 left halo + 800 + 16 right

// workspace layout (float offsets)
#define OFF_RMS 0
#define OFF_ZCR (OFF_RMS + NB*NF)
#define OFF_AMP (OFF_ZCR + NB*NF)
#define OFF_F0  (OFF_AMP + NB*NF)
#define OFF_VAL (OFF_F0  + NB*NF)
#define OFF_JIT (OFF_VAL + NB*NF)            // NB*4
#define OFF_HNR (OFF_JIT + NB*4)             // NB*NHNR_CHUNK*HNR_LAGS

__device__ __forceinline__ int imax_(int a, int b) { return a > b ? a : b; }

__device__ __forceinline__ uint pack_bf16(float a, float b) {
    uint ua = __builtin_bit_cast(uint, a), ub = __builtin_bit_cast(uint, b);
    ua = (ua + 0x8000u) >> 16; ub = (ub + 0x8000u) >> 16;
    return ua | (ub << 16);
}

__device__ __forceinline__ bf16x8 ld_b_frag(const uint* p) {
    union { uint u[4]; bf16x8 v; } t;
    t.u[0] = p[0]; t.u[1] = p[1]; t.u[2] = p[2]; t.u[3] = p[3];
    return t.v;
}

__device__ __forceinline__ float sgn_(float v) {
    return (float)(v > 0.f) - (float)(v < 0.f);
}

// ---------------------------------------------------------------------------
// K1: per-frame stats + autocorr peak via MFMA.  4 waves/block, 1 frame/wave.
// AC[16m+n] = sum_j sum_k x[32j+k-16m] * x[32j+k+n]   (A row-shift, B col-shift)
// x staged in LDS as bf16, dual copies (x, x<<1) so odd n is dword-aligned.
// Layout per copy: 496 zero pad | 400 data | 64 zero pad  = 960 elems.
// ---------------------------------------------------------------------------
__global__ __launch_bounds__(256) void k_frame(const float* __restrict__ audio,
                                               float* __restrict__ ws)
{
    __shared__ __align__(16) ushort sx[4][2][960];
    const int tid = threadIdx.x;
    const int widx = tid >> 6, lane = tid & 63;
    const int lo = lane & 15, q = lane >> 4;
    const int s = blockIdx.y;
    int f = blockIdx.x * 4 + widx;
    if (f > NF - 1) f = NF - 1;          // dup last frame (identical writes, benign)

    ushort* xw = &sx[widx][0][0];
    ushort* xo = &sx[widx][1][0];
    uint* xwd = (uint*)xw;
    uint* xod = (uint*)xo;

    // zero pads: dwords [0,248) and [448,480), both copies
    {
        uint4 z; z.x = 0; z.y = 0; z.z = 0; z.w = 0;
        for (int i = lane; i < 70; i += 64) {
            int d = (i < 62) ? (i * 4) : (448 + (i - 62) * 4);
            *(uint4*)(xwd + d) = z;
            *(uint4*)(xod + d) = z;
        }
    }

    // stage frame (fp32 -> bf16 dual copies) + fp32 stats in the same pass
    const float* a = audio + (size_t)s * NSAMP + (size_t)f * HOP;
    float ss = 0.f, zc = 0.f, amp = 0.f;
    for (int vi = lane; vi < 100; vi += 64) {
        float4 t = ((const float4*)a)[vi];
        float bn = (vi < 99) ? a[4 * vi + 4] : 0.f;
        ss += t.x * t.x + t.y * t.y + t.z * t.z + t.w * t.w;
        amp = fmaxf(amp, fmaxf(fmaxf(fabsf(t.x), fabsf(t.y)),
                               fmaxf(fabsf(t.z), fabsf(t.w))));
        zc += fabsf(sgn_(t.y) - sgn_(t.x)) + fabsf(sgn_(t.z) - sgn_(t.y))
            + fabsf(sgn_(t.w) - sgn_(t.z));
        if (vi < 99) zc += fabsf(sgn_(bn) - sgn_(t.w));
        int d = 248 + 2 * vi;
        xwd[d]     = pack_bf16(t.x, t.y);
        xwd[d + 1] = pack_bf16(t.z, t.w);
        xod[d]     = pack_bf16(t.y, t.z);
        xod[d + 1] = pack_bf16(t.w, bn);
    }
    #pragma unroll
    for (int off = 32; off; off >>= 1) {
        ss += __shfl_xor(ss, off);
        zc += __shfl_xor(zc, off);
        amp = fmaxf(amp, __shfl_xor(amp, off));
    }
    __syncthreads();

    // MFMA K-loop: C1 rows -> lags 0..255, C2 rows (m+16) -> lags 256..319
    f32x4 acc1 = {0.f, 0.f, 0.f, 0.f};
    f32x4 acc2 = {0.f, 0.f, 0.f, 0.f};
    const int aoff1 = 496 + 8 * q - 16 * lo;   // A1 start elem (16B aligned)
    const int aoff2 = aoff1 - 256;             // A2 (min 0 at lo=15,q=0 -> 0)
    const uint* bw = (const uint*)((lo & 1) ? xo : xw);
    const int boff = 248 + 4 * q + (lo >> 1);

    #pragma unroll
    for (int j = 0; j < 13; ++j) {
        bf16x8 a1 = *(const bf16x8*)(xw + aoff1 + 32 * j);
        bf16x8 a2 = *(const bf16x8*)(xw + aoff2 + 32 * j);
        bf16x8 b  = ld_b_frag(bw + boff + 16 * j);
        acc1 = __builtin_amdgcn_mfma_f32_16x16x32_bf16(a1, b, acc1, 0, 0, 0);
        acc2 = __builtin_amdgcn_mfma_f32_16x16x32_bf16(a2, b, acc2, 0, 0, 0);
    }

    // ac0 = lag 0 = row0 col0 = lane 0, reg 0
    float ac0 = __shfl(acc1[0], 0);

    // first-max argmax over lags [32,320); per-lane candidates in ascending lag
    float bv = -1e30f; int bl = 1 << 30;
    #pragma unroll
    for (int r = 0; r < 4; ++r) {
        int lag = 64 * q + 16 * r + lo;
        float v = acc1[r];
        if (lag >= 32 && v > bv) { bv = v; bl = lag; }
    }
    if (q == 0) {
        #pragma unroll
        for (int r = 0; r < 4; ++r) {
            int lag = 256 + 16 * r + lo;
            float v = acc2[r];
            if (v > bv) { bv = v; bl = lag; }
        }
    }
    #pragma unroll
    for (int off = 32; off; off >>= 1) {
        float ov = __shfl_xor(bv, off);
        int   ol = __shfl_xor(bl, off);
        if (ov > bv || (ov == bv && ol < bl)) { bv = ov; bl = ol; }
    }

    if (lane == 0) {
        float f0 = SR_F / (float)bl;
        int valid = (bv > 0.3f * ac0) && (f0 > 50.f) && (f0 < 500.f);
        size_t idx = (size_t)s * NF + f;
        ws[OFF_RMS + idx] = sqrtf(ss / (float)FRAME);
        ws[OFF_ZCR + idx] = zc / (2.f * (float)FRAME);
        ws[OFF_AMP + idx] = amp;
        ws[OFF_F0  + idx] = f0;
        ws[OFF_VAL + idx] = valid ? 1.f : 0.f;
    }
}

// ---------------------------------------------------------------------------
// K2: jitter — threshold crossings over whole waveform.  One block / sample.
// ---------------------------------------------------------------------------
__global__ __launch_bounds__(1024) void k_jitter(const float* __restrict__ audio,
                                                 float* __restrict__ ws)
{
    __shared__ unsigned long long msk[2500];   // 159999 flag bits
    __shared__ int   s_cnt[256], s_p0[256], s_p1[256], s_pl[256], s_pl2[256];
    __shared__ float s_sum[256];
    __shared__ float sred[16];
    __shared__ float s_thr;

    const int s = blockIdx.x;
    const int tid = threadIdx.x;
    const float* a = audio + (size_t)s * NSAMP;

    float m = 0.f;
    for (int i = tid; i < NSAMP; i += 1024) m = fmaxf(m, fabsf(a[i]));
    #pragma unroll
    for (int off = 32; off; off >>= 1) m = fmaxf(m, __shfl_xor(m, off));
    if ((tid & 63) == 0) sred[tid >> 6] = m;
    __syncthreads();
    if (tid == 0) {
        float mm = sred[0];
        for (int i = 1; i < 16; ++i) mm = fmaxf(mm, sred[i]);
        s_thr = 0.3f * mm;
    }
    __syncthreads();
    const float thr = s_thr;

    for (int base = 0; base < NSAMP - 1; base += 1024) {
        int i = base + tid;
        bool fl = (i < NSAMP - 1) && (a[i] < thr) && (a[i + 1] >= thr);
        unsigned long long bal = __ballot(fl);
        if ((tid & 63) == 0 && (base + tid) < NSAMP) msk[(base + tid) >> 6] = bal;
    }
    __syncthreads();

    if (tid < 250) {
        int cnt = 0, p0 = 0, p1 = 0, pl = 0, pl2 = 0;
        float sum = 0.f;
        for (int wi = 0; wi < 10; ++wi) {
            unsigned long long word = msk[tid * 10 + wi];
            int wb = (tid * 10 + wi) << 6;
            while (word) {
                int b = __builtin_ctzll(word);
                word &= word - 1;
                int pos = wb + b + 1;
                if (cnt >= 2) sum += fabsf((float)((pos - pl) - (pl - pl2)));
                if (cnt == 0) p0 = pos;
                if (cnt == 1) p1 = pos;
                pl2 = pl; pl = pos; ++cnt;
            }
        }
        s_cnt[tid] = cnt; s_p0[tid] = p0; s_p1[tid] = p1;
        s_pl[tid] = pl; s_pl2[tid] = pl2; s_sum[tid] = sum;
    }
    __syncthreads();

    if (tid == 0) {
        int Ac = 0, Ap0 = 0, Ap1 = 0, Apl = 0, Apl2 = 0; float As = 0.f;
        for (int c = 0; c < 250; ++c) {
            int rc = s_cnt[c]; if (!rc) continue;
            int rp0 = s_p0[c], rp1 = s_p1[c], rpl = s_pl[c], rpl2 = s_pl2[c];
            float rs = s_sum[c];
            if (Ac == 0) { Ac = rc; Ap0 = rp0; Ap1 = rp1; Apl = rpl; Apl2 = rpl2; As = rs; continue; }
            int pb = rp0 - Apl;
            As += rs;
            if (Ac >= 2) As += fabsf((float)(pb - (Apl - Apl2)));
            if (rc >= 2) As += fabsf((float)((rp1 - rp0) - pb));
            if (Ac == 1) Ap1 = rp0;
            Apl2 = (rc >= 2) ? rpl2 : Apl;
            Apl = rpl;
            Ac += rc;
        }
        float* j = ws + OFF_JIT + s * 4;
        j[0] = (float)Ac; j[1] = (float)Ap0; j[2] = (float)Apl; j[3] = As;
    }
}

// ---------------------------------------------------------------------------
// K3: HNR partial autocorr via MFMA, lags 50..199 (computed as 48+16m+n).
// 4 waves/block, 1 chunk/wave; 40 chunks x 125 j-steps; 5 tiles of 25 j.
// LDS window per tile: 288 left halo + 800 + 16 right = 1104 elems, dual copy.
// ---------------------------------------------------------------------------
__global__ __launch_bounds__(256) void k_hnr(const float* __restrict__ audio,
                                             float* __restrict__ ws)
{
    __shared__ __align__(16) ushort hx[4][2][HWIN];
    const int tid = threadIdx.x;
    const int widx = tid >> 6, lane = tid & 63;
    const int lo = lane & 15, q = lane >> 4;
    const int s = blockIdx.y;
    const int c = blockIdx.x * 4 + widx;                 // chunk id [0,40)
    const float* a = audio + (size_t)s * NSAMP;

    ushort* xw = &hx[widx][0][0];
    ushort* xo = &hx[widx][1][0];
    uint* xwd = (uint*)xw;
    uint* xod = (uint*)xo;

    const int aoff = 240 + 8 * q - 16 * lo;              // local elem, min 0
    const uint* bw = (const uint*)((lo & 1) ? xo : xw);
    const int boff = 144 + 4 * q + (lo >> 1);

    f32x4 acc = {0.f, 0.f, 0.f, 0.f};

    for (int tile = 0; tile < JCH / TJ; ++tile) {
        const int g0 = 32 * (c * JCH + tile * TJ) - 288; // global elem of local 0 (mult of 4)
        __syncthreads();
        for (int v = lane; v < HWIN / 4; v += 64) {
            int g = g0 + 4 * v;
            float x0, x1, x2, x3, x4;
            if (g >= 0 && g + 4 < NSAMP) {
                float4 t = *(const float4*)(a + g);
                x0 = t.x; x1 = t.y; x2 = t.z; x3 = t.w;
                x4 = a[g + 4];
            } else {
                x0 = (g     >= 0 && g     < NSAMP) ? a[g]     : 0.f;
                x1 = (g + 1 >= 0 && g + 1 < NSAMP) ? a[g + 1] : 0.f;
                x2 = (g + 2 >= 0 && g + 2 < NSAMP) ? a[g + 2] : 0.f;
                x3 = (g + 3 >= 0 && g + 3 < NSAMP) ? a[g + 3] : 0.f;
                x4 = (g + 4 >= 0 && g + 4 < NSAMP) ? a[g + 4] : 0.f;
            }
            xwd[2 * v]     = pack_bf16(x0, x1);
            xwd[2 * v + 1] = pack_bf16(x2, x3);
            xod[2 * v]     = pack_bf16(x1, x2);
            xod[2 * v + 1] = pack_bf16(x3, x4);
        }
        __syncthreads();

        #pragma unroll
        for (int jl = 0; jl < TJ; ++jl) {
            bf16x8 af = *(const bf16x8*)(xw + aoff + 32 * jl);
            bf16x8 bf = ld_b_frag(bw + boff + 16 * jl);
            acc = __builtin_amdgcn_mfma_f32_16x16x32_bf16(af, bf, acc, 0, 0, 0);
        }
    }

    // rows 0..9 valid: lag = 48 + 16*(4q+r) + lo; keep [50,200)
    #pragma unroll
    for (int r = 0; r < 4; ++r) {
        int row = 4 * q + r;
        int lag = 48 + 16 * row + lo;
        if (row < 10 && lag >= 50 && lag < 200)
            ws[OFF_HNR + ((size_t)s * NHNR_CHUNK + c) * HNR_LAGS + (lag - 50)] = acc[r];
    }
}

// ---------------------------------------------------------------------------
// K4: per-sample finalize (stats, shimmer, jitter gate, HNR percentile) + MLP
// ---------------------------------------------------------------------------
__global__ __launch_bounds__(256) void k_final(const float* __restrict__ ws,
        const float* __restrict__ W1, const float* __restrict__ b1,
        const float* __restrict__ gam, const float* __restrict__ bet,
        const float* __restrict__ W2, const float* __restrict__ b2,
        float* __restrict__ out)
{
    __shared__ float samp[NF];
    __shared__ float sac[HNR_LAGS];
    __shared__ float sred[32];
    __shared__ float sstat[12];
    __shared__ float sfeats[10];
    __shared__ float shid[64];

    const int s = blockIdx.x;
    const int tid = threadIdx.x;
    const float* rmsA = ws + OFF_RMS + (size_t)s * NF;
    const float* zcrA = ws + OFF_ZCR + (size_t)s * NF;
    const float* ampA = ws + OFF_AMP + (size_t)s * NF;
    const float* f0A  = ws + OFF_F0  + (size_t)s * NF;
    const float* valA = ws + OFF_VAL + (size_t)s * NF;

    float a0=0,a1=0,a2=0,a3=0,a4=0,a5=0,a6=0,a7=0;
    for (int i = tid; i < NF; i += 256) {
        float r = rmsA[i], z = zcrA[i], f0 = f0A[i], v = valA[i];
        samp[i] = ampA[i];
        a0 += r; a1 += r * r; a2 += z; a3 += z * z;
        a4 += f0 * v; a5 += f0 * f0 * v; a6 += v;
        a7 += (r > 0.01f && z < 0.3f) ? 1.f : 0.f;
    }
    #pragma unroll
    for (int off = 32; off; off >>= 1) {
        a0 += __shfl_xor(a0, off); a1 += __shfl_xor(a1, off);
        a2 += __shfl_xor(a2, off); a3 += __shfl_xor(a3, off);
        a4 += __shfl_xor(a4, off); a5 += __shfl_xor(a5, off);
        a6 += __shfl_xor(a6, off); a7 += __shfl_xor(a7, off);
    }
    if ((tid & 63) == 0) {
        int w = tid >> 6;
        sred[w*8+0]=a0; sred[w*8+1]=a1; sred[w*8+2]=a2; sred[w*8+3]=a3;
        sred[w*8+4]=a4; sred[w*8+5]=a5; sred[w*8+6]=a6; sred[w*8+7]=a7;
    }
    __syncthreads();

    if (tid < HNR_LAGS) {
        float acc = 0.f;
        const float* p = ws + OFF_HNR + (size_t)s * NHNR_CHUNK * HNR_LAGS + tid;
        for (int c = 0; c < NHNR_CHUNK; ++c) acc += p[c * HNR_LAGS];
        sac[tid] = acc;
    }
    if (tid == 0) {
        for (int k = 0; k < 8; ++k)
            sstat[k] = sred[k] + sred[8+k] + sred[16+k] + sred[24+k];
    }
    __syncthreads();

    if (tid < HNR_LAGS) {
        float v = sac[tid];
        int r = 0;
        for (int j = 0; j < HNR_LAGS; ++j) {
            float vj = sac[j];
            r += (vj < v) || (vj == v && j < tid);
        }
        if (r == 14) sstat[8] = v;
        if (r == 15) sstat[9] = v;
    }
    if (tid == 192) {
        float mx = sac[0];
        for (int j = 1; j < HNR_LAGS; ++j) mx = fmaxf(mx, sac[j]);
        sstat[10] = mx;
    }
    if (tid == 224) {
        int ka = 0; float sum_amp = 0.f, sum_ad = 0.f, prev = 0.f;
        for (int i = 0; i < NF; ++i) {
            float amp = samp[i];
            if (amp > 0.01f) {
                if (ka >= 1) sum_ad += fabsf(amp - prev);
                sum_amp += amp; prev = amp; ++ka;
            }
        }
        float mean_amp = sum_amp / (float)imax_(ka, 1);
        float mean_ad  = sum_ad  / (float)imax_(ka - 1, 1);
        sstat[11] = (ka >= 2 && mean_amp > 0.f)
            ? fminf(fmaxf(mean_ad / fmaxf(mean_amp, 1e-12f), 0.f), 1.f) : 0.f;
    }
    __syncthreads();

    if (tid == 0) {
        float S_r = sstat[0], S_r2 = sstat[1], S_z = sstat[2], S_z2 = sstat[3];
        float S_f = sstat[4], S_f2 = sstat[5], S_v = sstat[6], S_voi = sstat[7];
        float e_mean = S_r / (float)NF;
        float e_std  = sqrtf(fmaxf(S_r2 / (float)NF - e_mean * e_mean, 0.f));
        float z_mean = S_z / (float)NF;
        float z_std  = sqrtf(fmaxf(S_z2 / (float)NF - z_mean * z_mean, 0.f));
        float f0_mean = 0.f, f0_std = 0.f;
        if (S_v > 0.f) {
            f0_mean = S_f / S_v;
            f0_std  = sqrtf(fmaxf(S_f2 / S_v - f0_mean * f0_mean, 0.f));
        }
        const float* jp = ws + OFF_JIT + s * 4;
        int k = (int)jp[0];
        float pp0 = jp[1], ppl = jp[2], psum = jp[3];
        int nper = k - 1;
        float mean_period = (k >= 2) ? (ppl - pp0) / (float)(k - 1) : 0.f;
        float mean_pd = psum / (float)imax_(nper - 1, 1);
        float jit = (nper >= 2 && mean_period > 0.f)
            ? fminf(fmaxf(mean_pd / fmaxf(mean_period, 1e-12f), 0.f), 1.f) : 0.f;
        if (f0_mean < 50.f || f0_mean > 500.f) jit = 0.f;
        float noise = 0.1f * sstat[8] + 0.9f * sstat[9];
        float hnr = (noise > 0.f)
            ? fminf(fmaxf(sstat[10] / fmaxf(noise, 1e-30f) / 100.f, 0.f), 1.f) : 0.f;
        float shim = sstat[11];
        float voice = S_voi / (float)NF;

        float mt[10] = {f0_mean, f0_std, e_mean, e_std, z_mean, z_std, jit, shim, hnr, voice};
        for (int i = 0; i < 10; ++i) out[NB * 128 + s * 10 + i] = mt[i];
        sfeats[0] = f0_mean / 500.f;
        sfeats[1] = f0_std / 100.f;
        for (int i = 2; i < 10; ++i) sfeats[i] = mt[i];
    }
    __syncthreads();

    if (tid < 64) {
        float h = b1[tid];
        #pragma unroll
        for (int i = 0; i < 10; ++i) h = fmaf(sfeats[i], W1[tid * 10 + i], h);
        float sum = h, sq = h * h;
        #pragma unroll
        for (int off = 32; off; off >>= 1) {
            sum += __shfl_xor(sum, off);
            sq  += __shfl_xor(sq, off);
        }
        float mu = sum / 64.f;
        float var = sq / 64.f - mu * mu;
        float hn = (h - mu) * rsqrtf(var + 1e-5f) * gam[tid] + bet[tid];
        shid[tid] = fmaxf(hn, 0.f);
    }
    __syncthreads();
    if (tid < 128) {
        float accv = b2[tid];
        #pragma unroll 8
        for (int j = 0; j < 64; ++j) accv = fmaf(shid[j], W2[tid * 64 + j], accv);
        out[(size_t)s * 128 + tid] = accv;
    }
}

// ---------------------------------------------------------------------------
extern "C" void kernel_launch(void* const* d_in, const int* in_sizes, int n_in,
                              void* d_out, int out_size, void* d_ws, size_t ws_size,
                              hipStream_t stream)
{
    const float* audio = (const float*)d_in[0];
    const float* W1    = (const float*)d_in[1];
    const float* b1    = (const float*)d_in[2];
    const float* gam   = (const float*)d_in[3];
    const float* bet   = (const float*)d_in[4];
    const float* W2    = (const float*)d_in[5];
    const float* b2    = (const float*)d_in[6];
    float* out = (float*)d_out;
    float* ws  = (float*)d_ws;

    hipLaunchKernelGGL(k_frame,  dim3((NF + 3) / 4, NB),   dim3(256),  0, stream, audio, ws);
    hipLaunchKernelGGL(k_jitter, dim3(NB),                 dim3(1024), 0, stream, audio, ws);
    hipLaunchKernelGGL(k_hnr,    dim3(NHNR_CHUNK / 4, NB), dim3(256),  0, stream, audio, ws);
    hipLaunchKernelGGL(k_final,  dim3(NB),                 dim3(256),  0, stream,
                       ws, W1, b1, gam, bet, W2, b2, out);
}

// Round 4
// 454.583 us; speedup vs baseline: 2.9465x; 1.1329x over previous
//
#include <hip/hip_runtime.h>
#include <stdint.h>

typedef unsigned int uint;
typedef unsigned short ushort;
typedef __attribute__((ext_vector_type(8))) short bf16x8;
typedef __attribute__((ext_vector_type(4))) float f32x4;

#define SR_F 16000.0f
#define NSAMP 160000
#define NB 128
#define FRAME 400
#define HOP 160
#define NF 998
#define NHNR_CHUNK 40
#define JCH 125              // j-steps (32 samples each) per hnr chunk: 40*125*32 = 160000
#define HNR_LAGS 150
#define TJ 25                // j-steps per hnr tile (800 samples)
#define HWIN (32*TJ + 304)   // 1104 elems: 288 left halo + 800 + 16 right

// workspace layout (float offsets)
#define OFF_RMS 0
#define OFF_ZCR (OFF_RMS + NB*NF)
#define OFF_AMP (OFF_ZCR + NB*NF)
#define OFF_F0  (OFF_AMP + NB*NF)
#define OFF_VAL (OFF_F0  + NB*NF)
#define OFF_JIT (OFF_VAL + NB*NF)            // NB*4
#define OFF_HNR (OFF_JIT + NB*4)             // NB*NHNR_CHUNK*HNR_LAGS
#define OFF_MAX (OFF_HNR + NB*NHNR_CHUNK*HNR_LAGS)   // NB uints (|a| max bits)
#define OFF_MSK (OFF_MAX + NB)               // NB*2500 u64 (crossing bitmask), 8B-aligned

__device__ __forceinline__ int imax_(int a, int b) { return a > b ? a : b; }

__device__ __forceinline__ uint pack_bf16(float a, float b) {
    uint ua = __builtin_bit_cast(uint, a), ub = __builtin_bit_cast(uint, b);
    ua = (ua + 0x8000u) >> 16; ub = (ub + 0x8000u) >> 16;
    return ua | (ub << 16);
}

__device__ __forceinline__ bf16x8 ld_b_frag(const uint* p) {
    union { uint u[4]; bf16x8 v; } t;
    t.u[0] = p[0]; t.u[1] = p[1]; t.u[2] = p[2]; t.u[3] = p[3];
    return t.v;
}

__device__ __forceinline__ float sgn_(float v) {
    return (float)(v > 0.f) - (float)(v < 0.f);
}

// ---------------------------------------------------------------------------
// K1: per-frame stats + autocorr peak via MFMA.  4 waves/block, 1 frame/wave.
// ---------------------------------------------------------------------------
__global__ __launch_bounds__(256) void k_frame(const float* __restrict__ audio,
                                               float* __restrict__ ws)
{
    __shared__ __align__(16) ushort sx[4][2][960];
    const int tid = threadIdx.x;
    const int widx = tid >> 6, lane = tid & 63;
    const int lo = lane & 15, q = lane >> 4;
    const int s = blockIdx.y;
    int f = blockIdx.x * 4 + widx;
    if (f > NF - 1) f = NF - 1;          // dup last frame (identical writes, benign)

    ushort* xw = &sx[widx][0][0];
    ushort* xo = &sx[widx][1][0];
    uint* xwd = (uint*)xw;
    uint* xod = (uint*)xo;

    {
        uint4 z; z.x = 0; z.y = 0; z.z = 0; z.w = 0;
        for (int i = lane; i < 70; i += 64) {
            int d = (i < 62) ? (i * 4) : (448 + (i - 62) * 4);
            *(uint4*)(xwd + d) = z;
            *(uint4*)(xod + d) = z;
        }
    }

    const float* a = audio + (size_t)s * NSAMP + (size_t)f * HOP;
    float ss = 0.f, zc = 0.f, amp = 0.f;
    for (int vi = lane; vi < 100; vi += 64) {
        float4 t = ((const float4*)a)[vi];
        float bn = (vi < 99) ? a[4 * vi + 4] : 0.f;
        ss += t.x * t.x + t.y * t.y + t.z * t.z + t.w * t.w;
        amp = fmaxf(amp, fmaxf(fmaxf(fabsf(t.x), fabsf(t.y)),
                               fmaxf(fabsf(t.z), fabsf(t.w))));
        zc += fabsf(sgn_(t.y) - sgn_(t.x)) + fabsf(sgn_(t.z) - sgn_(t.y))
            + fabsf(sgn_(t.w) - sgn_(t.z));
        if (vi < 99) zc += fabsf(sgn_(bn) - sgn_(t.w));
        int d = 248 + 2 * vi;
        xwd[d]     = pack_bf16(t.x, t.y);
        xwd[d + 1] = pack_bf16(t.z, t.w);
        xod[d]     = pack_bf16(t.y, t.z);
        xod[d + 1] = pack_bf16(t.w, bn);
    }
    #pragma unroll
    for (int off = 32; off; off >>= 1) {
        ss += __shfl_xor(ss, off);
        zc += __shfl_xor(zc, off);
        amp = fmaxf(amp, __shfl_xor(amp, off));
    }
    __syncthreads();

    f32x4 acc1 = {0.f, 0.f, 0.f, 0.f};
    f32x4 acc2 = {0.f, 0.f, 0.f, 0.f};
    const int aoff1 = 496 + 8 * q - 16 * lo;
    const int aoff2 = aoff1 - 256;
    const uint* bw = (const uint*)((lo & 1) ? xo : xw);
    const int boff = 248 + 4 * q + (lo >> 1);

    #pragma unroll
    for (int j = 0; j < 13; ++j) {
        bf16x8 a1 = *(const bf16x8*)(xw + aoff1 + 32 * j);
        bf16x8 a2 = *(const bf16x8*)(xw + aoff2 + 32 * j);
        bf16x8 b  = ld_b_frag(bw + boff + 16 * j);
        acc1 = __builtin_amdgcn_mfma_f32_16x16x32_bf16(a1, b, acc1, 0, 0, 0);
        acc2 = __builtin_amdgcn_mfma_f32_16x16x32_bf16(a2, b, acc2, 0, 0, 0);
    }

    float ac0 = __shfl(acc1[0], 0);

    float bv = -1e30f; int bl = 1 << 30;
    #pragma unroll
    for (int r = 0; r < 4; ++r) {
        int lag = 64 * q + 16 * r + lo;
        float v = acc1[r];
        if (lag >= 32 && v > bv) { bv = v; bl = lag; }
    }
    if (q == 0) {
        #pragma unroll
        for (int r = 0; r < 4; ++r) {
            int lag = 256 + 16 * r + lo;
            float v = acc2[r];
            if (v > bv) { bv = v; bl = lag; }
        }
    }
    #pragma unroll
    for (int off = 32; off; off >>= 1) {
        float ov = __shfl_xor(bv, off);
        int   ol = __shfl_xor(bl, off);
        if (ov > bv || (ov == bv && ol < bl)) { bv = ov; bl = ol; }
    }

    if (lane == 0) {
        float f0 = SR_F / (float)bl;
        int valid = (bv > 0.3f * ac0) && (f0 > 50.f) && (f0 < 500.f);
        size_t idx = (size_t)s * NF + f;
        ws[OFF_RMS + idx] = sqrtf(ss / (float)FRAME);
        ws[OFF_ZCR + idx] = zc / (2.f * (float)FRAME);
        ws[OFF_AMP + idx] = amp;
        ws[OFF_F0  + idx] = f0;
        ws[OFF_VAL + idx] = valid ? 1.f : 0.f;
    }
}

// ---------------------------------------------------------------------------
// K2a: |a| max per sample.  20 blocks/sample, atomicMax on monotone uint bits.
// ---------------------------------------------------------------------------
__global__ __launch_bounds__(256) void k_absmax(const float* __restrict__ audio,
                                                float* __restrict__ ws)
{
    __shared__ float sred[4];
    const int s = blockIdx.y, b = blockIdx.x, tid = threadIdx.x;
    const float4* a = (const float4*)(audio + (size_t)s * NSAMP) + (size_t)b * 2000;
    float m = 0.f;
    for (int i = tid; i < 2000; i += 256) {
        float4 t = a[i];
        m = fmaxf(m, fmaxf(fmaxf(fabsf(t.x), fabsf(t.y)),
                           fmaxf(fabsf(t.z), fabsf(t.w))));
    }
    #pragma unroll
    for (int off = 32; off; off >>= 1) m = fmaxf(m, __shfl_xor(m, off));
    if ((tid & 63) == 0) sred[tid >> 6] = m;
    __syncthreads();
    if (tid == 0) {
        float mm = fmaxf(fmaxf(sred[0], sred[1]), fmaxf(sred[2], sred[3]));
        atomicMax((uint*)ws + OFF_MAX + s, __float_as_uint(mm));
    }
}

// ---------------------------------------------------------------------------
// K2b: crossing bitmask.  25 blocks/sample, ballot-packed to global.
// bit i set (i in [0,159999)) iff a[i] < thr && a[i+1] >= thr.
// ---------------------------------------------------------------------------
__global__ __launch_bounds__(256) void k_cross(const float* __restrict__ audio,
                                               float* __restrict__ ws)
{
    const int s = blockIdx.y, b = blockIdx.x, tid = threadIdx.x;
    const float thr = 0.3f * __uint_as_float(((const uint*)ws)[OFF_MAX + s]);
    const float* a = audio + (size_t)s * NSAMP;
    unsigned long long* msk =
        (unsigned long long*)(ws + OFF_MSK) + (size_t)s * 2500 + (size_t)b * 100;
    const int base0 = b * 6400;
    #pragma unroll 5
    for (int it = 0; it < 25; ++it) {
        int i = base0 + it * 256 + tid;
        bool fl = (i < NSAMP - 1) && (a[i] < thr) && (a[i + 1] >= thr);
        unsigned long long bal = __ballot(fl);
        if ((tid & 63) == 0) msk[(it * 256 + tid) >> 6] = bal;
    }
}

// ---------------------------------------------------------------------------
// K2c: stitch — chunk states over the bitmask, associative merge.
// ---------------------------------------------------------------------------
__global__ __launch_bounds__(256) void k_jstitch(float* __restrict__ ws)
{
    __shared__ unsigned long long msk[2500];
    __shared__ int   s_cnt[256], s_p0[256], s_p1[256], s_pl[256], s_pl2[256];
    __shared__ float s_sum[256];
    const int s = blockIdx.x, tid = threadIdx.x;
    const unsigned long long* gm =
        (const unsigned long long*)(ws + OFF_MSK) + (size_t)s * 2500;
    for (int i = tid; i < 2500; i += 256) msk[i] = gm[i];
    __syncthreads();

    if (tid < 250) {
        int cnt = 0, p0 = 0, p1 = 0, pl = 0, pl2 = 0;
        float sum = 0.f;
        for (int wi = 0; wi < 10; ++wi) {
            unsigned long long word = msk[tid * 10 + wi];
            int wb = (tid * 10 + wi) << 6;
            while (word) {
                int b = __builtin_ctzll(word);
                word &= word - 1;
                int pos = wb + b + 1;
                if (cnt >= 2) sum += fabsf((float)((pos - pl) - (pl - pl2)));
                if (cnt == 0) p0 = pos;
                if (cnt == 1) p1 = pos;
                pl2 = pl; pl = pos; ++cnt;
            }
        }
        s_cnt[tid] = cnt; s_p0[tid] = p0; s_p1[tid] = p1;
        s_pl[tid] = pl; s_pl2[tid] = pl2; s_sum[tid] = sum;
    }
    __syncthreads();

    if (tid == 0) {
        int Ac = 0, Ap0 = 0, Ap1 = 0, Apl = 0, Apl2 = 0; float As = 0.f;
        for (int c = 0; c < 250; ++c) {
            int rc = s_cnt[c]; if (!rc) continue;
            int rp0 = s_p0[c], rp1 = s_p1[c], rpl = s_pl[c], rpl2 = s_pl2[c];
            float rs = s_sum[c];
            if (Ac == 0) { Ac = rc; Ap0 = rp0; Ap1 = rp1; Apl = rpl; Apl2 = rpl2; As = rs; continue; }
            int pb = rp0 - Apl;
            As += rs;
            if (Ac >= 2) As += fabsf((float)(pb - (Apl - Apl2)));
            if (rc >= 2) As += fabsf((float)((rp1 - rp0) - pb));
            if (Ac == 1) Ap1 = rp0;
            Apl2 = (rc >= 2) ? rpl2 : Apl;
            Apl = rpl;
            Ac += rc;
        }
        float* j = ws + OFF_JIT + s * 4;
        j[0] = (float)Ac; j[1] = (float)Ap0; j[2] = (float)Apl; j[3] = As;
    }
}

// ---------------------------------------------------------------------------
// K3: HNR partial autocorr via MFMA, lags 50..199 (as 48+16m+n).
// ---------------------------------------------------------------------------
__global__ __launch_bounds__(256) void k_hnr(const float* __restrict__ audio,
                                             float* __restrict__ ws)
{
    __shared__ __align__(16) ushort hx[4][2][HWIN];
    const int tid = threadIdx.x;
    const int widx = tid >> 6, lane = tid & 63;
    const int lo = lane & 15, q = lane >> 4;
    const int s = blockIdx.y;
    const int c = blockIdx.x * 4 + widx;
    const float* a = audio + (size_t)s * NSAMP;

    ushort* xw = &hx[widx][0][0];
    ushort* xo = &hx[widx][1][0];
    uint* xwd = (uint*)xw;
    uint* xod = (uint*)xo;

    const int aoff = 240 + 8 * q - 16 * lo;
    const uint* bw = (const uint*)((lo & 1) ? xo : xw);
    const int boff = 144 + 4 * q + (lo >> 1);

    f32x4 acc = {0.f, 0.f, 0.f, 0.f};

    for (int tile = 0; tile < JCH / TJ; ++tile) {
        const int g0 = 32 * (c * JCH + tile * TJ) - 288;
        __syncthreads();
        for (int v = lane; v < HWIN / 4; v += 64) {
            int g = g0 + 4 * v;
            float x0, x1, x2, x3, x4;
            if (g >= 0 && g + 4 < NSAMP) {
                float4 t = *(const float4*)(a + g);
                x0 = t.x; x1 = t.y; x2 = t.z; x3 = t.w;
                x4 = a[g + 4];
            } else {
                x0 = (g     >= 0 && g     < NSAMP) ? a[g]     : 0.f;
                x1 = (g + 1 >= 0 && g + 1 < NSAMP) ? a[g + 1] : 0.f;
                x2 = (g + 2 >= 0 && g + 2 < NSAMP) ? a[g + 2] : 0.f;
                x3 = (g + 3 >= 0 && g + 3 < NSAMP) ? a[g + 3] : 0.f;
                x4 = (g + 4 >= 0 && g + 4 < NSAMP) ? a[g + 4] : 0.f;
            }
            xwd[2 * v]     = pack_bf16(x0, x1);
            xwd[2 * v + 1] = pack_bf16(x2, x3);
            xod[2 * v]     = pack_bf16(x1, x2);
            xod[2 * v + 1] = pack_bf16(x3, x4);
        }
        __syncthreads();

        #pragma unroll
        for (int jl = 0; jl < TJ; ++jl) {
            bf16x8 af = *(const bf16x8*)(xw + aoff + 32 * jl);
            bf16x8 bf = ld_b_frag(bw + boff + 16 * jl);
            acc = __builtin_amdgcn_mfma_f32_16x16x32_bf16(af, bf, acc, 0, 0, 0);
        }
    }

    #pragma unroll
    for (int r = 0; r < 4; ++r) {
        int row = 4 * q + r;
        int lag = 48 + 16 * row + lo;
        if (row < 10 && lag >= 50 && lag < 200)
            ws[OFF_HNR + ((size_t)s * NHNR_CHUNK + c) * HNR_LAGS + (lag - 50)] = acc[r];
    }
}

// ---------------------------------------------------------------------------
// K4: per-sample finalize + MLP
// ---------------------------------------------------------------------------
__global__ __launch_bounds__(256) void k_final(const float* __restrict__ ws,
        const float* __restrict__ W1, const float* __restrict__ b1,
        const float* __restrict__ gam, const float* __restrict__ bet,
        const float* __restrict__ W2, const float* __restrict__ b2,
        float* __restrict__ out)
{
    __shared__ float samp[NF];
    __shared__ float sac[HNR_LAGS];
    __shared__ float sred[32];
    __shared__ float sstat[12];
    __shared__ float sfeats[10];
    __shared__ float shid[64];

    const int s = blockIdx.x;
    const int tid = threadIdx.x;
    const float* rmsA = ws + OFF_RMS + (size_t)s * NF;
    const float* zcrA = ws + OFF_ZCR + (size_t)s * NF;
    const float* ampA = ws + OFF_AMP + (size_t)s * NF;
    const float* f0A  = ws + OFF_F0  + (size_t)s * NF;
    const float* valA = ws + OFF_VAL + (size_t)s * NF;

    float a0=0,a1=0,a2=0,a3=0,a4=0,a5=0,a6=0,a7=0;
    for (int i = tid; i < NF; i += 256) {
        float r = rmsA[i], z = zcrA[i], f0 = f0A[i], v = valA[i];
        samp[i] = ampA[i];
        a0 += r; a1 += r * r; a2 += z; a3 += z * z;
        a4 += f0 * v; a5 += f0 * f0 * v; a6 += v;
        a7 += (r > 0.01f && z < 0.3f) ? 1.f : 0.f;
    }
    #pragma unroll
    for (int off = 32; off; off >>= 1) {
        a0 += __shfl_xor(a0, off); a1 += __shfl_xor(a1, off);
        a2 += __shfl_xor(a2, off); a3 += __shfl_xor(a3, off);
        a4 += __shfl_xor(a4, off); a5 += __shfl_xor(a5, off);
        a6 += __shfl_xor(a6, off); a7 += __shfl_xor(a7, off);
    }
    if ((tid & 63) == 0) {
        int w = tid >> 6;
        sred[w*8+0]=a0; sred[w*8+1]=a1; sred[w*8+2]=a2; sred[w*8+3]=a3;
        sred[w*8+4]=a4; sred[w*8+5]=a5; sred[w*8+6]=a6; sred[w*8+7]=a7;
    }
    __syncthreads();

    if (tid < HNR_LAGS) {
        float acc = 0.f;
        const float* p = ws + OFF_HNR + (size_t)s * NHNR_CHUNK * HNR_LAGS + tid;
        for (int c = 0; c < NHNR_CHUNK; ++c) acc += p[c * HNR_LAGS];
        sac[tid] = acc;
    }
    if (tid == 0) {
        for (int k = 0; k < 8; ++k)
            sstat[k] = sred[k] + sred[8+k] + sred[16+k] + sred[24+k];
    }
    __syncthreads();

    if (tid < HNR_LAGS) {
        float v = sac[tid];
        int r = 0;
        for (int j = 0; j < HNR_LAGS; ++j) {
            float vj = sac[j];
            r += (vj < v) || (vj == v && j < tid);
        }
        if (r == 14) sstat[8] = v;
        if (r == 15) sstat[9] = v;
    }
    if (tid == 192) {
        float mx = sac[0];
        for (int j = 1; j < HNR_LAGS; ++j) mx = fmaxf(mx, sac[j]);
        sstat[10] = mx;
    }
    if (tid == 224) {
        int ka = 0; float sum_amp = 0.f, sum_ad = 0.f, prev = 0.f;
        for (int i = 0; i < NF; ++i) {
            float amp = samp[i];
            if (amp > 0.01f) {
                if (ka >= 1) sum_ad += fabsf(amp - prev);
                sum_amp += amp; prev = amp; ++ka;
            }
        }
        float mean_amp = sum_amp / (float)imax_(ka, 1);
        float mean_ad  = sum_ad  / (float)imax_(ka - 1, 1);
        sstat[11] = (ka >= 2 && mean_amp > 0.f)
            ? fminf(fmaxf(mean_ad / fmaxf(mean_amp, 1e-12f), 0.f), 1.f) : 0.f;
    }
    __syncthreads();

    if (tid == 0) {
        float S_r = sstat[0], S_r2 = sstat[1], S_z = sstat[2], S_z2 = sstat[3];
        float S_f = sstat[4], S_f2 = sstat[5], S_v = sstat[6], S_voi = sstat[7];
        float e_mean = S_r / (float)NF;
        float e_std  = sqrtf(fmaxf(S_r2 / (float)NF - e_mean * e_mean, 0.f));
        float z_mean = S_z / (float)NF;
        float z_std  = sqrtf(fmaxf(S_z2 / (float)NF - z_mean * z_mean, 0.f));
        float f0_mean = 0.f, f0_std = 0.f;
        if (S_v > 0.f) {
            f0_mean = S_f / S_v;
            f0_std  = sqrtf(fmaxf(S_f2 / S_v - f0_mean * f0_mean, 0.f));
        }
        const float* jp = ws + OFF_JIT + s * 4;
        int k = (int)jp[0];
        float pp0 = jp[1], ppl = jp[2], psum = jp[3];
        int nper = k - 1;
        float mean_period = (k >= 2) ? (ppl - pp0) / (float)(k - 1) : 0.f;
        float mean_pd = psum / (float)imax_(nper - 1, 1);
        float jit = (nper >= 2 && mean_period > 0.f)
            ? fminf(fmaxf(mean_pd / fmaxf(mean_period, 1e-12f), 0.f), 1.f) : 0.f;
        if (f0_mean < 50.f || f0_mean > 500.f) jit = 0.f;
        float noise = 0.1f * sstat[8] + 0.9f * sstat[9];
        float hnr = (noise > 0.f)
            ? fminf(fmaxf(sstat[10] / fmaxf(noise, 1e-30f) / 100.f, 0.f), 1.f) : 0.f;
        float shim = sstat[11];
        float voice = S_voi / (float)NF;

        float mt[10] = {f0_mean, f0_std, e_mean, e_std, z_mean, z_std, jit, shim, hnr, voice};
        for (int i = 0; i < 10; ++i) out[NB * 128 + s * 10 + i] = mt[i];
        sfeats[0] = f0_mean / 500.f;
        sfeats[1] = f0_std / 100.f;
        for (int i = 2; i < 10; ++i) sfeats[i] = mt[i];
    }
    __syncthreads();

    if (tid < 64) {
        float h = b1[tid];
        #pragma unroll
        for (int i = 0; i < 10; ++i) h = fmaf(sfeats[i], W1[tid * 10 + i], h);
        float sum = h, sq = h * h;
        #pragma unroll
        for (int off = 32; off; off >>= 1) {
            sum += __shfl_xor(sum, off);
            sq  += __shfl_xor(sq, off);
        }
        float mu = sum / 64.f;
        float var = sq / 64.f - mu * mu;
        float hn = (h - mu) * rsqrtf(var + 1e-5f) * gam[tid] + bet[tid];
        shid[tid] = fmaxf(hn, 0.f);
    }
    __syncthreads();
    if (tid < 128) {
        float accv = b2[tid];
        #pragma unroll 8
        for (int j = 0; j < 64; ++j) accv = fmaf(shid[j], W2[tid * 64 + j], accv);
        out[(size_t)s * 128 + tid] = accv;
    }
}

// ---------------------------------------------------------------------------
extern "C" void kernel_launch(void* const* d_in, const int* in_sizes, int n_in,
                              void* d_out, int out_size, void* d_ws, size_t ws_size,
                              hipStream_t stream)
{
    const float* audio = (const float*)d_in[0];
    const float* W1    = (const float*)d_in[1];
    const float* b1    = (const float*)d_in[2];
    const float* gam   = (const float*)d_in[3];
    const float* bet   = (const float*)d_in[4];
    const float* W2    = (const float*)d_in[5];
    const float* b2    = (const float*)d_in[6];
    float* out = (float*)d_out;
    float* ws  = (float*)d_ws;

    hipMemsetAsync((uint*)ws + OFF_MAX, 0, NB * sizeof(uint), stream);
    hipLaunchKernelGGL(k_frame,   dim3((NF + 3) / 4, NB),   dim3(256), 0, stream, audio, ws);
    hipLaunchKernelGGL(k_absmax,  dim3(20, NB),             dim3(256), 0, stream, audio, ws);
    hipLaunchKernelGGL(k_cross,   dim3(25, NB),             dim3(256), 0, stream, audio, ws);
    hipLaunchKernelGGL(k_jstitch, dim3(NB),                 dim3(256), 0, stream, ws);
    hipLaunchKernelGGL(k_hnr,     dim3(NHNR_CHUNK / 4, NB), dim3(256), 0, stream, audio, ws);
    hipLaunchKernelGGL(k_final,   dim3(NB),                 dim3(256), 0, stream,
                       ws, W1, b1, gam, bet, W2, b2, out);
}